// Round 18
// baseline (26721.912 us; speedup 1.0000x reference)
//
#include <hip/hip_runtime.h>
#include <hip/hip_bf16.h>
#include <math.h>

// Problem constants
constexpr int kB = 4;
constexpr int kN = 2048;
constexpr int kC = 256;
constexpr int kDFF = 1024;
constexpr int kKNN = 16;
constexpr int kDH = 64;

__device__ __forceinline__ float gelu_erf(float x) {
    return 0.5f * x * (1.0f + erff(x * 0.70710678118654752440f));
}

// ---------------------------------------------------------------------------
// ROUND 18: full pipeline, FP32 OUTPUT (the round-17 revelation: out dtype is
// float32; the bf16 branch in the traceback was never the taken branch).
// Kernels are the thrice-audited naive versions from R4.
// ---------------------------------------------------------------------------

__global__ __launch_bounds__(256) void naive_proj(
    const float* __restrict__ src, const float* __restrict__ Wp,
    const float* __restrict__ bp, float* __restrict__ x)
{
    const int id = blockIdx.x * 256 + threadIdx.x;   // < 8192*256
    const int o = id & 255;
    const int r = id >> 8;
    const int n = r & 2047;
    const int b = r >> 11;
    const float* s = src + (size_t)b * kC * kN;
    float acc = 0.0f;
    for (int c = 0; c < kC; c++)
        acc = fmaf(Wp[o * kC + c], s[(size_t)c * kN + n], acc);
    x[(size_t)id] = acc + bp[o];
}

__global__ __launch_bounds__(256) void naive_ln(
    float* __restrict__ x, const float* __restrict__ g, const float* __restrict__ bb)
{
    const int row = blockIdx.x * 256 + threadIdx.x;  // < 8192
    float* p = x + (size_t)row * kC;
    float s = 0.0f;
    for (int c = 0; c < kC; c++) s += p[c];
    const float mean = s * (1.0f / kC);
    float s2 = 0.0f;
    for (int c = 0; c < kC; c++) { float d = p[c] - mean; s2 += d * d; }
    const float var = s2 * (1.0f / kC);
    const float r = 1.0f / sqrtf(var + 1e-5f);
    for (int c = 0; c < kC; c++) p[c] = (p[c] - mean) * r * g[c] + bb[c];
}

__global__ __launch_bounds__(256) void naive_knn(
    const float* __restrict__ pos,
    const float* __restrict__ Wr1, const float* __restrict__ br1,
    const float* __restrict__ Wr2, const float* __restrict__ br2,
    int* __restrict__ idx_out, float* __restrict__ bias_out)
{
    __shared__ float px[kN], py[kN], pz[kN], sq[kN];
    const int b = blockIdx.y;
    const int t = threadIdx.x;
    const int n = blockIdx.x * 256 + t;
    const float* pb = pos + (size_t)b * 3 * kN;
    for (int m = t; m < kN; m += 256) {
        float x = pb[m], y = pb[kN + m], z = pb[2 * kN + m];
        px[m] = x; py[m] = y; pz[m] = z;
        sq[m] = __fadd_rn(__fadd_rn(__fmul_rn(x, x), __fmul_rn(y, y)), __fmul_rn(z, z));
    }
    __syncthreads();

    const float qx = px[n], qy = py[n], qz = pz[n], qsq = sq[n];
    const float br2v = br2[0];

    float lastd = -1e30f; int lastm = -1;
    const size_t obase = ((size_t)b * kN + n) * kKNN;

    for (int r = 0; r < kKNN; r++) {
        float best = 1e30f; int bid = kN;
        for (int m = 0; m < kN; m++) {
            float dot = __fadd_rn(__fadd_rn(__fmul_rn(qx, px[m]), __fmul_rn(qy, py[m])),
                                  __fmul_rn(qz, pz[m]));
            float d = __fsub_rn(__fadd_rn(qsq, sq[m]), __fmul_rn(2.0f, dot));
            bool after = (d > lastd) || (d == lastd && m > lastm);
            if (after && d < best) { best = d; bid = m; }
        }
        lastd = best; lastm = bid;

        const float rx = qx - px[bid], ry = qy - py[bid], rz = qz - pz[bid];
        float sum = 0.0f;
        for (int o = 0; o < 64; o++) {
            float h = rx * Wr1[o * 3 + 0] + ry * Wr1[o * 3 + 1] +
                      rz * Wr1[o * 3 + 2] + br1[o];
            sum += gelu_erf(h) * Wr2[o];
        }
        idx_out[obase + r]  = bid;
        bias_out[obase + r] = sum + br2v;
    }
}

__global__ __launch_bounds__(256) void naive_gemm(
    const float* __restrict__ A, const float* __restrict__ W,
    const float* __restrict__ bias, const float* __restrict__ resid,
    float* __restrict__ out, int M, int Nout, int K, int epi)
{
    const int id = blockIdx.x * 256 + threadIdx.x;   // < M*Nout
    const int n = id % Nout;
    const int m = id / Nout;
    const float* a = A + (size_t)m * K;
    const float* w = W + (size_t)n * K;
    float acc = 0.0f;
    for (int k = 0; k < K; k++) acc = fmaf(a[k], w[k], acc);
    float v = acc + bias[n];
    if (resid) v += resid[(size_t)id];
    if (epi == 1) v = gelu_erf(v);
    out[(size_t)id] = v;
}

__global__ __launch_bounds__(256) void naive_attn(
    const float* __restrict__ q, const float* __restrict__ kbuf,
    const float* __restrict__ vbuf, const int* __restrict__ idx,
    const float* __restrict__ bias, float* __restrict__ obuf)
{
    const int id = blockIdx.x * 256 + threadIdx.x;   // < 8192*4
    const int h = id & 3;
    const int r = id >> 2;
    const size_t row = (size_t)r;
    const float* qp = q + row * kC + h * kDH;

    float sc[kKNN];
    int   sj[kKNN];
    #pragma unroll
    for (int j = 0; j < kKNN; j++) {
        int m = idx[row * kKNN + j];
        sj[j] = m;
        const float* kp = kbuf + ((size_t)(r & ~2047) + m) * kC + h * kDH;
        float dot = 0.0f;
        for (int d = 0; d < kDH; d++) dot = fmaf(qp[d], kp[d], dot);
        sc[j] = dot * 0.125f + bias[row * kKNN + j];
    }
    float mx = sc[0];
    #pragma unroll
    for (int j = 1; j < kKNN; j++) mx = fmaxf(mx, sc[j]);
    float den = 0.0f;
    #pragma unroll
    for (int j = 0; j < kKNN; j++) { sc[j] = expf(sc[j] - mx); den += sc[j]; }
    const float inv = 1.0f / den;

    float* op = obuf + row * kC + h * kDH;
    for (int d = 0; d < kDH; d++) {
        float o = 0.0f;
        #pragma unroll
        for (int j = 0; j < kKNN; j++) {
            const float* vp = vbuf + ((size_t)(r & ~2047) + sj[j]) * kC + h * kDH;
            o = fmaf(sc[j] * inv, vp[d], o);
        }
        op[d] = o;
    }
}

// transpose (b,n,c) f32 -> (b,c,n) F32 OUTPUT (no bf16 cast!)
__global__ __launch_bounds__(256) void naive_transpose_f32(
    const float* __restrict__ z, float* __restrict__ out)
{
    const int id = blockIdx.x * 256 + threadIdx.x;   // < B*C*N
    const int n = id & 2047;
    const int r = id >> 11;
    const int c = r & 255;
    const int b = r >> 8;
    out[(size_t)id] = z[((size_t)b * kN + n) * kC + c];
}

// ---------------------------------------------------------------------------
extern "C" void kernel_launch(void* const* d_in, const int* in_sizes, int n_in,
                              void* d_out, int out_size, void* d_ws, size_t ws_size,
                              hipStream_t stream)
{
    const float* src1 = (const float*)d_in[0];
    const float* src2 = (const float*)d_in[1];
    const float* pos  = (const float*)d_in[2];
    const float* Wp   = (const float*)d_in[3];
    const float* bp   = (const float*)d_in[4];
    const float* Wr1  = (const float*)d_in[5];
    const float* br1  = (const float*)d_in[6];
    const float* Wr2  = (const float*)d_in[7];
    const float* br2  = (const float*)d_in[8];
    const float* Wqkv = (const float*)d_in[9];
    const float* bqkv = (const float*)d_in[10];
    const float* Wo   = (const float*)d_in[11];
    const float* bo   = (const float*)d_in[12];
    const float* g13  = (const float*)d_in[13];
    const float* b13  = (const float*)d_in[14];
    const float* g12  = (const float*)d_in[15];
    const float* b12  = (const float*)d_in[16];
    const float* W1   = (const float*)d_in[17];
    const float* b1   = (const float*)d_in[18];
    const float* W2   = (const float*)d_in[19];
    const float* b2   = (const float*)d_in[20];
    float* out = (float*)d_out;          // <-- FP32 output

    const size_t S = (size_t)kB * kN * kC;  // 2,097,152 floats
    float* ws = (float*)d_ws;
    float* x1 = ws;            // LN13(s1), resid for out-proj
    float* x2 = ws + S;
    float* qb = ws + 2 * S;
    float* kb = ws + 3 * S;
    float* vb = ws + 4 * S;
    float* ob = ws + 5 * S;
    float* yb = ws + 6 * S;    // LN12 result, FFN input + resid
    float* hb = ws + 2 * S;    // alias qb..ob (dead by FFN1): 4S floats
    float* zb = ws + S;        // alias x2 (dead after v-projection)
    int*   idxb  = (int*)(ws + 7 * S);
    float* biasb = ws + 7 * S + (size_t)kB * kN * kKNN;

    const int M = kB * kN;  // 8192

    // 1) input projections
    naive_proj<<<8192, 256, 0, stream>>>(src1, Wp, bp, x1);
    naive_proj<<<8192, 256, 0, stream>>>(src2, Wp, bp, x2);

    // 2) LN13 in place
    naive_ln<<<32, 256, 0, stream>>>(x1, g13, b13);
    naive_ln<<<32, 256, 0, stream>>>(x2, g13, b13);

    // 3) KNN + rel-pos bias
    naive_knn<<<dim3(kN / 256, kB), 256, 0, stream>>>(pos, Wr1, br1, Wr2, br2, idxb, biasb);

    // 4) q/k/v projections
    naive_gemm<<<8192, 256, 0, stream>>>(x1, Wqkv, bqkv, nullptr, qb, M, kC, kC, 0);
    naive_gemm<<<8192, 256, 0, stream>>>(x2, Wqkv + (size_t)kC * kC, bqkv + kC, nullptr, kb, M, kC, kC, 0);
    naive_gemm<<<8192, 256, 0, stream>>>(x2, Wqkv + (size_t)2 * kC * kC, bqkv + 2 * kC, nullptr, vb, M, kC, kC, 0);

    // 5) sparse attention
    naive_attn<<<128, 256, 0, stream>>>(qb, kb, vb, idxb, biasb, ob);

    // 6) out-proj + residual(x1=LN13(s1)), then LN12 in place
    naive_gemm<<<8192, 256, 0, stream>>>(ob, Wo, bo, x1, yb, M, kC, kC, 0);
    naive_ln<<<32, 256, 0, stream>>>(yb, g12, b12);

    // 7) FFN
    naive_gemm<<<32768, 256, 0, stream>>>(yb, W1, b1, nullptr, hb, M, kDFF, kC, 1);
    naive_gemm<<<8192, 256, 0, stream>>>(hb, W2, b2, yb, zb, M, kC, kDFF, 0);

    // 8) transpose to (b, c, n), FP32 out
    naive_transpose_f32<<<8192, 256, 0, stream>>>(zb, out);
}

// Round 19
// 780.294 us; speedup vs baseline: 34.2460x; 34.2460x over previous
//
#include <hip/hip_runtime.h>
#include <hip/hip_bf16.h>
#include <math.h>

// Problem constants
constexpr int kB = 4;
constexpr int kN = 2048;
constexpr int kC = 256;
constexpr int kDFF = 1024;
constexpr int kKNN = 16;
constexpr int kDH = 64;

__device__ __forceinline__ float gelu_erf(float x) {
    return 0.5f * x * (1.0f + erff(x * 0.70710678118654752440f));
}

// ---------------------------------------------------------------------------
// 1) input_proj tiled: s[b][n][o] = sum_c Wp[o][c]*src[b][c][n] + bp[o]
//    grid: (kC/64, kN/64, 8)  z<4 -> src1, z>=4 -> src2
// ---------------------------------------------------------------------------
__global__ __launch_bounds__(256) void proj_gemm(
    const float* __restrict__ src1, const float* __restrict__ src2,
    const float* __restrict__ Wp, const float* __restrict__ bp,
    float* __restrict__ x1, float* __restrict__ x2)
{
    constexpr int BM = 64, BN = 64, BK = 16;
    __shared__ float As[BK][BM + 1];
    __shared__ float Bs[BK][BN + 1];

    const int z = blockIdx.z;
    const int b = z & 3;
    const float* A = (z < 4 ? src1 : src2) + (size_t)b * kC * kN;  // (C x N)
    float* out = (z < 4 ? x1 : x2) + (size_t)b * kN * kC;

    const int tid = threadIdx.x;
    const int n0 = blockIdx.x * BN;
    const int m0 = blockIdx.y * BM;
    const int tx = tid & 15, ty = tid >> 4;

    float acc[4][4] = {};
    for (int k0 = 0; k0 < kC; k0 += BK) {
        #pragma unroll
        for (int q = 0; q < 4; q++) {
            int e = tid + q * 256;
            int kk = e >> 6, mm = e & 63;               // coalesced over mm (n dim)
            As[kk][mm] = A[(size_t)(k0 + kk) * kN + (m0 + mm)];
        }
        #pragma unroll
        for (int q = 0; q < 4; q++) {
            int e = tid + q * 256;
            int nn = e >> 4, kk = e & 15;               // coalesced over kk
            Bs[kk][nn] = Wp[(size_t)(n0 + nn) * kC + (k0 + kk)];
        }
        __syncthreads();
        #pragma unroll
        for (int kk = 0; kk < BK; kk++) {
            float a[4], bb[4];
            #pragma unroll
            for (int i = 0; i < 4; i++) a[i] = As[kk][ty * 4 + i];
            #pragma unroll
            for (int j = 0; j < 4; j++) bb[j] = Bs[kk][tx * 4 + j];
            #pragma unroll
            for (int i = 0; i < 4; i++)
                #pragma unroll
                for (int j = 0; j < 4; j++) acc[i][j] += a[i] * bb[j];
        }
        __syncthreads();
    }
    #pragma unroll
    for (int i = 0; i < 4; i++) {
        int m = m0 + ty * 4 + i;
        #pragma unroll
        for (int j = 0; j < 4; j++) {
            int n = n0 + tx * 4 + j;
            out[(size_t)m * kC + n] = acc[i][j] + bp[n];
        }
    }
}

// ---------------------------------------------------------------------------
// 2) tiled GEMM: out = epi(A @ W^T + bias [+ resid]); epi 1 = exact GELU
// ---------------------------------------------------------------------------
__global__ __launch_bounds__(256) void gemm_f32(
    const float* __restrict__ A, const float* __restrict__ W,
    const float* __restrict__ bias, const float* __restrict__ resid,
    float* __restrict__ out, int M, int Nout, int K, int epi)
{
    constexpr int BM = 64, BN = 64, BK = 16;
    __shared__ float As[BK][BM + 1];
    __shared__ float Bs[BK][BN + 1];

    const int tid = threadIdx.x;
    const int n0 = blockIdx.x * BN;
    const int m0 = blockIdx.y * BM;
    const int tx = tid & 15, ty = tid >> 4;

    float acc[4][4] = {};
    for (int k0 = 0; k0 < K; k0 += BK) {
        #pragma unroll
        for (int q = 0; q < 4; q++) {
            int e = tid + q * 256;
            int mm = e >> 4, kk = e & 15;
            As[kk][mm] = A[(size_t)(m0 + mm) * K + (k0 + kk)];
        }
        #pragma unroll
        for (int q = 0; q < 4; q++) {
            int e = tid + q * 256;
            int nn = e >> 4, kk = e & 15;
            Bs[kk][nn] = W[(size_t)(n0 + nn) * K + (k0 + kk)];
        }
        __syncthreads();
        #pragma unroll
        for (int kk = 0; kk < BK; kk++) {
            float a[4], bb[4];
            #pragma unroll
            for (int i = 0; i < 4; i++) a[i] = As[kk][ty * 4 + i];
            #pragma unroll
            for (int j = 0; j < 4; j++) bb[j] = Bs[kk][tx * 4 + j];
            #pragma unroll
            for (int i = 0; i < 4; i++)
                #pragma unroll
                for (int j = 0; j < 4; j++) acc[i][j] += a[i] * bb[j];
        }
        __syncthreads();
    }
    #pragma unroll
    for (int i = 0; i < 4; i++) {
        int m = m0 + ty * 4 + i;
        #pragma unroll
        for (int j = 0; j < 4; j++) {
            int n = n0 + tx * 4 + j;
            float v = acc[i][j] + bias[n];
            if (resid) v += resid[(size_t)m * Nout + n];
            if (epi == 1) v = gelu_erf(v);
            out[(size_t)m * Nout + n] = v;
        }
    }
}

// ---------------------------------------------------------------------------
// 3) LayerNorm over C=256, one block per row, in place.
// ---------------------------------------------------------------------------
__global__ __launch_bounds__(256) void ln_kernel(
    float* __restrict__ x, const float* __restrict__ g, const float* __restrict__ bb)
{
    const size_t row = blockIdx.x;
    const int t = threadIdx.x;
    float v = x[row * kC + t];

    __shared__ float red4[4];
    float s = v;
    #pragma unroll
    for (int off = 32; off; off >>= 1) s += __shfl_xor(s, off, 64);
    if ((t & 63) == 0) red4[t >> 6] = s;
    __syncthreads();
    float mean = (red4[0] + red4[1] + red4[2] + red4[3]) * (1.0f / kC);

    float d = v - mean;
    float s2 = d * d;
    #pragma unroll
    for (int off = 32; off; off >>= 1) s2 += __shfl_xor(s2, off, 64);
    __syncthreads();
    if ((t & 63) == 0) red4[t >> 6] = s2;
    __syncthreads();
    float var = (red4[0] + red4[1] + red4[2] + red4[3]) * (1.0f / kC);

    float r = 1.0f / sqrtf(var + 1e-5f);
    x[row * kC + t] = d * r * g[t] + bb[t];
}

// ---------------------------------------------------------------------------
// 4) cooperative KNN: one block per query; 256 threads share the scan.
//    Tie-break = lowest index (matches top_k).  Strict IEEE fp32 distances.
// ---------------------------------------------------------------------------
__global__ __launch_bounds__(256) void knn_kernel(
    const float* __restrict__ pos,
    const float* __restrict__ Wr1, const float* __restrict__ br1,
    const float* __restrict__ Wr2, const float* __restrict__ br2,
    int* __restrict__ idx_out, float* __restrict__ bias_out)
{
    const int n = blockIdx.x;
    const int b = blockIdx.y;
    const int t = threadIdx.x;

    __shared__ float px[kN], py[kN], pz[kN], sq[kN];
    const float* pb = pos + (size_t)b * 3 * kN;
    for (int m = t; m < kN; m += 256) {
        float x = pb[m], y = pb[kN + m], z = pb[2 * kN + m];
        px[m] = x; py[m] = y; pz[m] = z;
        sq[m] = __fadd_rn(__fadd_rn(__fmul_rn(x, x), __fmul_rn(y, y)), __fmul_rn(z, z));
    }
    __syncthreads();

    const float qx = px[n], qy = py[n], qz = pz[n], qsq = sq[n];

    float cd[8];
    #pragma unroll
    for (int j = 0; j < 8; j++) {
        int m = j * 256 + t;
        float dot = __fadd_rn(__fadd_rn(__fmul_rn(qx, px[m]), __fmul_rn(qy, py[m])),
                              __fmul_rn(qz, pz[m]));
        cd[j] = __fsub_rn(__fadd_rn(qsq, sq[m]), __fmul_rn(2.0f, dot));
    }

    __shared__ float sd[256];
    __shared__ int   si[256];
    __shared__ int   sel[kKNN];
    unsigned mask = 0;

    for (int r = 0; r < kKNN; r++) {
        float best = 1e30f; int bid = kN;
        #pragma unroll
        for (int j = 0; j < 8; j++) {
            if (mask & (1u << j)) continue;
            int m = j * 256 + t;
            float d = cd[j];
            if (d < best || (d == best && m < bid)) { best = d; bid = m; }
        }
        sd[t] = best; si[t] = bid;
        __syncthreads();
        for (int s = 128; s > 0; s >>= 1) {
            if (t < s) {
                float d2 = sd[t + s]; int i2 = si[t + s];
                if (d2 < sd[t] || (d2 == sd[t] && i2 < si[t])) { sd[t] = d2; si[t] = i2; }
            }
            __syncthreads();
        }
        int w = si[0];
        if (t == 0) sel[r] = w;
        if ((w & 255) == t) mask |= 1u << (w >> 8);
        __syncthreads();
    }

    // bias MLP: thread t -> neighbor k=t>>4, hidden quarter part=t&15 (4 units)
    __shared__ float red[256];
    const int k = t >> 4;
    const int part = t & 15;
    const int m = sel[k];
    const float rx = qx - px[m], ry = qy - py[m], rz = qz - pz[m];
    float partial = 0.0f;
    #pragma unroll
    for (int jj = 0; jj < 4; jj++) {
        int o = part * 4 + jj;
        float h = rx * Wr1[o * 3 + 0] + ry * Wr1[o * 3 + 1] +
                  rz * Wr1[o * 3 + 2] + br1[o];
        partial += gelu_erf(h) * Wr2[o];
    }
    red[t] = partial;
    __syncthreads();
    if (t < kKNN) {
        float s = 0.0f;
        for (int i = 0; i < 16; i++) s += red[t * 16 + i];
        size_t o = ((size_t)b * kN + n) * kKNN + t;
        idx_out[o] = sel[t];
        bias_out[o] = s + br2[0];
    }
}

// ---------------------------------------------------------------------------
// 5) sparse attention: block = (n, b), 4 waves = 4 heads, lane = d.
// ---------------------------------------------------------------------------
__global__ __launch_bounds__(256) void attn_kernel(
    const float* __restrict__ q, const float* __restrict__ kbuf,
    const float* __restrict__ vbuf, const int* __restrict__ idx,
    const float* __restrict__ bias, float* __restrict__ obuf)
{
    const int n = blockIdx.x;
    const int b = blockIdx.y;
    const int t = threadIdx.x;
    const int h = t >> 6;
    const int d = t & 63;

    const size_t row = (size_t)b * kN + n;
    const float qv = q[row * kC + h * kDH + d];

    __shared__ int   sidx[kKNN];
    __shared__ float sb[kKNN];
    if (t < kKNN) { sidx[t] = idx[row * kKNN + t]; sb[t] = bias[row * kKNN + t]; }
    __syncthreads();

    float sc[kKNN];
    #pragma unroll
    for (int j = 0; j < kKNN; j++) {
        size_t kr = (size_t)b * kN + sidx[j];
        float p = qv * kbuf[kr * kC + h * kDH + d];
        #pragma unroll
        for (int off = 32; off; off >>= 1) p += __shfl_xor(p, off, 64);
        sc[j] = p * 0.125f + sb[j];
    }
    float mx = sc[0];
    #pragma unroll
    for (int j = 1; j < kKNN; j++) mx = fmaxf(mx, sc[j]);
    float den = 0.0f;
    #pragma unroll
    for (int j = 0; j < kKNN; j++) { sc[j] = expf(sc[j] - mx); den += sc[j]; }
    const float inv = 1.0f / den;
    float o = 0.0f;
    #pragma unroll
    for (int j = 0; j < kKNN; j++) {
        size_t kr = (size_t)b * kN + sidx[j];
        o += sc[j] * inv * vbuf[kr * kC + h * kDH + d];
    }
    obuf[row * kC + h * kDH + d] = o;
}

// ---------------------------------------------------------------------------
// 6) LDS-tiled transpose (b,n,c) f32 -> (b,c,n) f32 out.
// ---------------------------------------------------------------------------
__global__ __launch_bounds__(256) void transpose_f32(
    const float* __restrict__ z, float* __restrict__ out)
{
    __shared__ float tile[32][33];
    const int b = blockIdx.z;
    const int n0 = blockIdx.x * 32;
    const int c0 = blockIdx.y * 32;
    const int tx = threadIdx.x;   // 32
    const int ty = threadIdx.y;   // 8
    #pragma unroll
    for (int i = 0; i < 32; i += 8)
        tile[ty + i][tx] = z[(size_t)b * kN * kC + (size_t)(n0 + ty + i) * kC + (c0 + tx)];
    __syncthreads();
    #pragma unroll
    for (int i = 0; i < 32; i += 8)
        out[(size_t)b * kC * kN + (size_t)(c0 + ty + i) * kN + (n0 + tx)] =
            tile[tx][ty + i];
}

// ---------------------------------------------------------------------------
extern "C" void kernel_launch(void* const* d_in, const int* in_sizes, int n_in,
                              void* d_out, int out_size, void* d_ws, size_t ws_size,
                              hipStream_t stream)
{
    const float* src1 = (const float*)d_in[0];
    const float* src2 = (const float*)d_in[1];
    const float* pos  = (const float*)d_in[2];
    const float* Wp   = (const float*)d_in[3];
    const float* bp   = (const float*)d_in[4];
    const float* Wr1  = (const float*)d_in[5];
    const float* br1  = (const float*)d_in[6];
    const float* Wr2  = (const float*)d_in[7];
    const float* br2  = (const float*)d_in[8];
    const float* Wqkv = (const float*)d_in[9];
    const float* bqkv = (const float*)d_in[10];
    const float* Wo   = (const float*)d_in[11];
    const float* bo   = (const float*)d_in[12];
    const float* g13  = (const float*)d_in[13];
    const float* b13  = (const float*)d_in[14];
    const float* g12  = (const float*)d_in[15];
    const float* b12  = (const float*)d_in[16];
    const float* W1   = (const float*)d_in[17];
    const float* b1   = (const float*)d_in[18];
    const float* W2   = (const float*)d_in[19];
    const float* b2   = (const float*)d_in[20];
    float* out = (float*)d_out;                      // fp32 output (b,c,n)

    const size_t S = (size_t)kB * kN * kC;  // 2,097,152 floats
    float* ws = (float*)d_ws;
    float* x1 = ws;            // LN13(s1); resid for out-proj
    float* x2 = ws + S;
    float* qb = ws + 2 * S;
    float* kb = ws + 3 * S;
    float* vb = ws + 4 * S;
    float* ob = ws + 5 * S;
    float* yb = ws + 6 * S;    // LN12 result; FFN input + resid
    float* hb = ws + 2 * S;    // alias qb..ob (dead by FFN1): 4S floats
    float* zb = ws + S;        // alias x2 (dead after v-projection)
    int*   idxb  = (int*)(ws + 7 * S);
    float* biasb = ws + 7 * S + (size_t)kB * kN * kKNN;

    const int M = kB * kN;  // 8192

    // 1) input projections (both sources, one launch)
    proj_gemm<<<dim3(kC / 64, kN / 64, 8), 256, 0, stream>>>(src1, src2, Wp, bp, x1, x2);

    // 2) LN13 in place
    ln_kernel<<<M, 256, 0, stream>>>(x1, g13, b13);
    ln_kernel<<<M, 256, 0, stream>>>(x2, g13, b13);

    // 3) KNN + rel-pos bias
    knn_kernel<<<dim3(kN, kB), 256, 0, stream>>>(pos, Wr1, br1, Wr2, br2, idxb, biasb);

    // 4) q/k/v projections
    gemm_f32<<<dim3(kC / 64, M / 64), 256, 0, stream>>>(x1, Wqkv, bqkv, nullptr, qb, M, kC, kC, 0);
    gemm_f32<<<dim3(kC / 64, M / 64), 256, 0, stream>>>(x2, Wqkv + (size_t)kC * kC, bqkv + kC,
                                                        nullptr, kb, M, kC, kC, 0);
    gemm_f32<<<dim3(kC / 64, M / 64), 256, 0, stream>>>(x2, Wqkv + (size_t)2 * kC * kC, bqkv + 2 * kC,
                                                        nullptr, vb, M, kC, kC, 0);

    // 5) sparse attention
    attn_kernel<<<dim3(kN, kB), 256, 0, stream>>>(qb, kb, vb, idxb, biasb, ob);

    // 6) out-proj + residual(x1), then LN12
    gemm_f32<<<dim3(kC / 64, M / 64), 256, 0, stream>>>(ob, Wo, bo, x1, yb, M, kC, kC, 0);
    ln_kernel<<<M, 256, 0, stream>>>(yb, g12, b12);

    // 7) FFN
    gemm_f32<<<dim3(kDFF / 64, M / 64), 256, 0, stream>>>(yb, W1, b1, nullptr, hb, M, kDFF, kC, 1);
    gemm_f32<<<dim3(kC / 64, M / 64), 256, 0, stream>>>(hb, W2, b2, yb, zb, M, kC, kDFF, 0);

    // 8) transpose to (b,c,n), fp32
    transpose_f32<<<dim3(kN / 32, kC / 32, kB), dim3(32, 8), 0, stream>>>(zb, out);
}

// Round 20
// 448.486 us; speedup vs baseline: 59.5824x; 1.7398x over previous
//
#include <hip/hip_runtime.h>
#include <hip/hip_bf16.h>
#include <math.h>

// Problem constants
constexpr int kB = 4;
constexpr int kN = 2048;
constexpr int kC = 256;
constexpr int kDFF = 1024;
constexpr int kKNN = 16;
constexpr int kDH = 64;

typedef __attribute__((ext_vector_type(8))) short short8;
typedef __attribute__((ext_vector_type(4))) float float4v;

__device__ __forceinline__ float gelu_erf(float x) {
    return 0.5f * x * (1.0f + erff(x * 0.70710678118654752440f));
}

// fp32 -> bf16 bits, round-to-nearest-even (bit-exact with HW conversion)
__device__ __forceinline__ short f2b(float f) {
    unsigned u = __float_as_uint(f);
    u = u + 0x7FFFu + ((u >> 16) & 1u);
    return (short)(u >> 16);
}

// ---------------------------------------------------------------------------
// 1) input_proj tiled fp32 (src is K-major; only 2 GF -- stays on vector ALU)
// ---------------------------------------------------------------------------
__global__ __launch_bounds__(256) void proj_gemm(
    const float* __restrict__ src1, const float* __restrict__ src2,
    const float* __restrict__ Wp, const float* __restrict__ bp,
    float* __restrict__ x1, float* __restrict__ x2)
{
    constexpr int BM = 64, BN = 64, BK = 16;
    __shared__ float As[BK][BM + 1];
    __shared__ float Bs[BK][BN + 1];

    const int z = blockIdx.z;
    const int b = z & 3;
    const float* A = (z < 4 ? src1 : src2) + (size_t)b * kC * kN;  // (C x N)
    float* out = (z < 4 ? x1 : x2) + (size_t)b * kN * kC;

    const int tid = threadIdx.x;
    const int n0 = blockIdx.x * BN;
    const int m0 = blockIdx.y * BM;
    const int tx = tid & 15, ty = tid >> 4;

    float acc[4][4] = {};
    for (int k0 = 0; k0 < kC; k0 += BK) {
        #pragma unroll
        for (int q = 0; q < 4; q++) {
            int e = tid + q * 256;
            int kk = e >> 6, mm = e & 63;
            As[kk][mm] = A[(size_t)(k0 + kk) * kN + (m0 + mm)];
        }
        #pragma unroll
        for (int q = 0; q < 4; q++) {
            int e = tid + q * 256;
            int nn = e >> 4, kk = e & 15;
            Bs[kk][nn] = Wp[(size_t)(n0 + nn) * kC + (k0 + kk)];
        }
        __syncthreads();
        #pragma unroll
        for (int kk = 0; kk < BK; kk++) {
            float a[4], bb[4];
            #pragma unroll
            for (int i = 0; i < 4; i++) a[i] = As[kk][ty * 4 + i];
            #pragma unroll
            for (int j = 0; j < 4; j++) bb[j] = Bs[kk][tx * 4 + j];
            #pragma unroll
            for (int i = 0; i < 4; i++)
                #pragma unroll
                for (int j = 0; j < 4; j++) acc[i][j] += a[i] * bb[j];
        }
        __syncthreads();
    }
    #pragma unroll
    for (int i = 0; i < 4; i++) {
        int m = m0 + ty * 4 + i;
        #pragma unroll
        for (int j = 0; j < 4; j++) {
            int n = n0 + tx * 4 + j;
            out[(size_t)m * kC + n] = acc[i][j] + bp[n];
        }
    }
}

// ---------------------------------------------------------------------------
// 2) MFMA GEMM: out = epi(A @ W^T + bias [+resid]).  A (MxK) f32 row-major,
//    W (NxK) f32 row-major.  bf16 fragments, fp32 accumulate.
//    Block 256 = 4 waves; tile 64x64; BK=32.  Wave w: rows w*16..w*16+15.
//    Frag layouts (verified m89/m120): A[m=lane&15][k=quad*8+j];
//    B[k=quad*8+j][n=lane&15]; D col=lane&15 row=quad*4+reg.
// ---------------------------------------------------------------------------
__global__ __launch_bounds__(256) void mfma_gemm(
    const float* __restrict__ A, const float* __restrict__ W,
    const float* __restrict__ bias, const float* __restrict__ resid,
    float* __restrict__ out, int M, int Nout, int K, int epi)
{
    __shared__ __align__(16) short Asm[64][40];   // 32 data + 8 pad (16B-aligned rows)
    __shared__ __align__(16) short Bsm[64][40];

    const int tid = threadIdx.x;
    const int n0 = blockIdx.x * 64;
    const int m0 = blockIdx.y * 64;
    const int lane = tid & 63, wv = tid >> 6;
    const int lm = lane & 15, quad = lane >> 4;
    const int r = tid >> 2, q = tid & 3;          // staging: row r, k-quarter q

    float4v acc[4] = {};

    for (int k0 = 0; k0 < K; k0 += 32) {
        // stage A tile (64 x 32) and W tile (64 x 32) as bf16
        {
            const float* ap = A + (size_t)(m0 + r) * K + k0 + q * 8;
            short8 av;
            #pragma unroll
            for (int j = 0; j < 8; j++) av[j] = f2b(ap[j]);
            *(short8*)&Asm[r][q * 8] = av;
            const float* wp = W + (size_t)(n0 + r) * K + k0 + q * 8;
            short8 bv;
            #pragma unroll
            for (int j = 0; j < 8; j++) bv[j] = f2b(wp[j]);
            *(short8*)&Bsm[r][q * 8] = bv;
        }
        __syncthreads();

        short8 af = *(const short8*)&Asm[wv * 16 + lm][quad * 8];
        #pragma unroll
        for (int j4 = 0; j4 < 4; j4++) {
            short8 bf = *(const short8*)&Bsm[j4 * 16 + lm][quad * 8];
            acc[j4] = __builtin_amdgcn_mfma_f32_16x16x32_bf16(af, bf, acc[j4], 0, 0, 0);
        }
        __syncthreads();
    }

    #pragma unroll
    for (int j4 = 0; j4 < 4; j4++) {
        const int n = n0 + j4 * 16 + lm;
        const float bn = bias[n];
        #pragma unroll
        for (int rg = 0; rg < 4; rg++) {
            const int m = m0 + wv * 16 + quad * 4 + rg;
            float v = acc[j4][rg] + bn;
            if (resid) v += resid[(size_t)m * Nout + n];
            if (epi == 1) v = gelu_erf(v);
            out[(size_t)m * Nout + n] = v;
        }
    }
}

// ---------------------------------------------------------------------------
// 3) LayerNorm over C=256, one block per row, in place.
// ---------------------------------------------------------------------------
__global__ __launch_bounds__(256) void ln_kernel(
    float* __restrict__ x, const float* __restrict__ g, const float* __restrict__ bb)
{
    const size_t row = blockIdx.x;
    const int t = threadIdx.x;
    float v = x[row * kC + t];

    __shared__ float red4[4];
    float s = v;
    #pragma unroll
    for (int off = 32; off; off >>= 1) s += __shfl_xor(s, off, 64);
    if ((t & 63) == 0) red4[t >> 6] = s;
    __syncthreads();
    float mean = (red4[0] + red4[1] + red4[2] + red4[3]) * (1.0f / kC);

    float d = v - mean;
    float s2 = d * d;
    #pragma unroll
    for (int off = 32; off; off >>= 1) s2 += __shfl_xor(s2, off, 64);
    __syncthreads();
    if ((t & 63) == 0) red4[t >> 6] = s2;
    __syncthreads();
    float var = (red4[0] + red4[1] + red4[2] + red4[3]) * (1.0f / kC);

    float r = 1.0f / sqrtf(var + 1e-5f);
    x[row * kC + t] = d * r * g[t] + bb[t];
}

// ---------------------------------------------------------------------------
// 4) wave-per-query KNN: block = 4 waves = 4 queries; barrier-free selection.
//    Identical strict-IEEE distance expression as before => same selection.
// ---------------------------------------------------------------------------
__global__ __launch_bounds__(256) void knn_kernel(
    const float* __restrict__ pos,
    const float* __restrict__ Wr1, const float* __restrict__ br1,
    const float* __restrict__ Wr2, const float* __restrict__ br2,
    int* __restrict__ idx_out, float* __restrict__ bias_out)
{
    __shared__ float px[kN], py[kN], pz[kN], sq[kN];
    __shared__ int selS[4][kKNN];

    const int b = blockIdx.y;
    const int t = threadIdx.x;
    const int lane = t & 63, wv = t >> 6;
    const int n = blockIdx.x * 4 + wv;

    const float* pb = pos + (size_t)b * 3 * kN;
    for (int m = t; m < kN; m += 256) {
        float x = pb[m], y = pb[kN + m], z = pb[2 * kN + m];
        px[m] = x; py[m] = y; pz[m] = z;
        sq[m] = __fadd_rn(__fadd_rn(__fmul_rn(x, x), __fmul_rn(y, y)), __fmul_rn(z, z));
    }
    __syncthreads();

    const float qx = px[n], qy = py[n], qz = pz[n], qsq = sq[n];

    // candidate m = c*64 + lane, c = 0..31
    float cd[32];
    #pragma unroll
    for (int c = 0; c < 32; c++) {
        int m = c * 64 + lane;
        float dot = __fadd_rn(__fadd_rn(__fmul_rn(qx, px[m]), __fmul_rn(qy, py[m])),
                              __fmul_rn(qz, pz[m]));
        cd[c] = __fsub_rn(__fadd_rn(qsq, sq[m]), __fmul_rn(2.0f, dot));
    }

    unsigned mask = 0;
    for (int r = 0; r < kKNN; r++) {
        float best = 1e30f; int bid = kN;
        #pragma unroll
        for (int c = 0; c < 32; c++) {
            if (mask & (1u << c)) continue;
            int m = c * 64 + lane;
            float d = cd[c];
            if (d < best || (d == best && m < bid)) { best = d; bid = m; }
        }
        // wave butterfly lex-min (no barriers)
        #pragma unroll
        for (int off = 1; off < 64; off <<= 1) {
            float od = __shfl_xor(best, off, 64);
            int   oi = __shfl_xor(bid, off, 64);
            if (od < best || (od == best && oi < bid)) { best = od; bid = oi; }
        }
        if (lane == 0) selS[wv][r] = bid;
        if ((bid & 63) == lane) mask |= 1u << (bid >> 6);
    }

    // bias MLP: lane = (neighbor k = lane>>2, quarter part = lane&3)
    const int k = lane >> 2;
    const int part = lane & 3;
    const int m = selS[wv][k];
    const float rx = qx - px[m], ry = qy - py[m], rz = qz - pz[m];
    float partial = 0.0f;
    #pragma unroll
    for (int jj = 0; jj < 16; jj++) {
        int o = part * 16 + jj;
        float h = rx * Wr1[o * 3 + 0] + ry * Wr1[o * 3 + 1] +
                  rz * Wr1[o * 3 + 2] + br1[o];
        partial += gelu_erf(h) * Wr2[o];
    }
    partial += __shfl_xor(partial, 1, 64);
    partial += __shfl_xor(partial, 2, 64);
    if (part == 0) {
        size_t o = ((size_t)b * kN + n) * kKNN + k;
        idx_out[o] = m;
        bias_out[o] = partial + br2[0];
    }
}

// ---------------------------------------------------------------------------
// 5) sparse attention: block = (n, b), 4 waves = 4 heads, lane = d.
// ---------------------------------------------------------------------------
__global__ __launch_bounds__(256) void attn_kernel(
    const float* __restrict__ q, const float* __restrict__ kbuf,
    const float* __restrict__ vbuf, const int* __restrict__ idx,
    const float* __restrict__ bias, float* __restrict__ obuf)
{
    const int n = blockIdx.x;
    const int b = blockIdx.y;
    const int t = threadIdx.x;
    const int h = t >> 6;
    const int d = t & 63;

    const size_t row = (size_t)b * kN + n;
    const float qv = q[row * kC + h * kDH + d];

    __shared__ int   sidx[kKNN];
    __shared__ float sb[kKNN];
    if (t < kKNN) { sidx[t] = idx[row * kKNN + t]; sb[t] = bias[row * kKNN + t]; }
    __syncthreads();

    float sc[kKNN];
    #pragma unroll
    for (int j = 0; j < kKNN; j++) {
        size_t kr = (size_t)b * kN + sidx[j];
        float p = qv * kbuf[kr * kC + h * kDH + d];
        #pragma unroll
        for (int off = 32; off; off >>= 1) p += __shfl_xor(p, off, 64);
        sc[j] = p * 0.125f + sb[j];
    }
    float mx = sc[0];
    #pragma unroll
    for (int j = 1; j < kKNN; j++) mx = fmaxf(mx, sc[j]);
    float den = 0.0f;
    #pragma unroll
    for (int j = 0; j < kKNN; j++) { sc[j] = expf(sc[j] - mx); den += sc[j]; }
    const float inv = 1.0f / den;
    float o = 0.0f;
    #pragma unroll
    for (int j = 0; j < kKNN; j++) {
        size_t kr = (size_t)b * kN + sidx[j];
        o += sc[j] * inv * vbuf[kr * kC + h * kDH + d];
    }
    obuf[row * kC + h * kDH + d] = o;
}

// ---------------------------------------------------------------------------
// 6) LDS-tiled transpose (b,n,c) f32 -> (b,c,n) f32 out.
// ---------------------------------------------------------------------------
__global__ __launch_bounds__(256) void transpose_f32(
    const float* __restrict__ z, float* __restrict__ out)
{
    __shared__ float tile[32][33];
    const int b = blockIdx.z;
    const int n0 = blockIdx.x * 32;
    const int c0 = blockIdx.y * 32;
    const int tx = threadIdx.x;   // 32
    const int ty = threadIdx.y;   // 8
    #pragma unroll
    for (int i = 0; i < 32; i += 8)
        tile[ty + i][tx] = z[(size_t)b * kN * kC + (size_t)(n0 + ty + i) * kC + (c0 + tx)];
    __syncthreads();
    #pragma unroll
    for (int i = 0; i < 32; i += 8)
        out[(size_t)b * kC * kN + (size_t)(c0 + ty + i) * kN + (n0 + tx)] =
            tile[tx][ty + i];
}

// ---------------------------------------------------------------------------
extern "C" void kernel_launch(void* const* d_in, const int* in_sizes, int n_in,
                              void* d_out, int out_size, void* d_ws, size_t ws_size,
                              hipStream_t stream)
{
    const float* src1 = (const float*)d_in[0];
    const float* src2 = (const float*)d_in[1];
    const float* pos  = (const float*)d_in[2];
    const float* Wp   = (const float*)d_in[3];
    const float* bp   = (const float*)d_in[4];
    const float* Wr1  = (const float*)d_in[5];
    const float* br1  = (const float*)d_in[6];
    const float* Wr2  = (const float*)d_in[7];
    const float* br2  = (const float*)d_in[8];
    const float* Wqkv = (const float*)d_in[9];
    const float* bqkv = (const float*)d_in[10];
    const float* Wo   = (const float*)d_in[11];
    const float* bo   = (const float*)d_in[12];
    const float* g13  = (const float*)d_in[13];
    const float* b13  = (const float*)d_in[14];
    const float* g12  = (const float*)d_in[15];
    const float* b12  = (const float*)d_in[16];
    const float* W1   = (const float*)d_in[17];
    const float* b1   = (const float*)d_in[18];
    const float* W2   = (const float*)d_in[19];
    const float* b2   = (const float*)d_in[20];
    float* out = (float*)d_out;                      // fp32 output (b,c,n)

    const size_t S = (size_t)kB * kN * kC;  // 2,097,152 floats
    float* ws = (float*)d_ws;
    float* x1 = ws;            // LN13(s1); resid for out-proj
    float* x2 = ws + S;
    float* qb = ws + 2 * S;
    float* kb = ws + 3 * S;
    float* vb = ws + 4 * S;
    float* ob = ws + 5 * S;
    float* yb = ws + 6 * S;    // LN12 result; FFN input + resid
    float* hb = ws + 2 * S;    // alias qb..ob (dead by FFN1): 4S floats
    float* zb = ws + S;        // alias x2 (dead after v-projection)
    int*   idxb  = (int*)(ws + 7 * S);
    float* biasb = ws + 7 * S + (size_t)kB * kN * kKNN;

    const int M = kB * kN;  // 8192

    // 1) input projections
    proj_gemm<<<dim3(kC / 64, kN / 64, 8), 256, 0, stream>>>(src1, src2, Wp, bp, x1, x2);

    // 2) LN13 in place
    ln_kernel<<<M, 256, 0, stream>>>(x1, g13, b13);
    ln_kernel<<<M, 256, 0, stream>>>(x2, g13, b13);

    // 3) KNN + rel-pos bias (wave-per-query)
    knn_kernel<<<dim3(kN / 4, kB), 256, 0, stream>>>(pos, Wr1, br1, Wr2, br2, idxb, biasb);

    // 4) q/k/v projections (MFMA)
    mfma_gemm<<<dim3(kC / 64, M / 64), 256, 0, stream>>>(x1, Wqkv, bqkv, nullptr, qb, M, kC, kC, 0);
    mfma_gemm<<<dim3(kC / 64, M / 64), 256, 0, stream>>>(x2, Wqkv + (size_t)kC * kC, bqkv + kC,
                                                         nullptr, kb, M, kC, kC, 0);
    mfma_gemm<<<dim3(kC / 64, M / 64), 256, 0, stream>>>(x2, Wqkv + (size_t)2 * kC * kC, bqkv + 2 * kC,
                                                         nullptr, vb, M, kC, kC, 0);

    // 5) sparse attention
    attn_kernel<<<dim3(kN, kB), 256, 0, stream>>>(qb, kb, vb, idxb, biasb, ob);

    // 6) out-proj + residual(x1), then LN12  (MFMA)
    mfma_gemm<<<dim3(kC / 64, M / 64), 256, 0, stream>>>(ob, Wo, bo, x1, yb, M, kC, kC, 0);
    ln_kernel<<<M, 256, 0, stream>>>(yb, g12, b12);

    // 7) FFN (MFMA)
    mfma_gemm<<<dim3(kDFF / 64, M / 64), 256, 0, stream>>>(yb, W1, b1, nullptr, hb, M, kDFF, kC, 1);
    mfma_gemm<<<dim3(kC / 64, M / 64), 256, 0, stream>>>(hb, W2, b2, yb, zb, M, kC, kDFF, 0);

    // 8) transpose to (b,c,n), fp32
    transpose_f32<<<dim3(kN / 32, kC / 32, kB), dim3(32, 8), 0, stream>>>(zb, out);
}